// Round 15
// baseline (233.800 us; speedup 1.0000x reference)
//
#include <hip/hip_runtime.h>

typedef _Float16 f16;
typedef __attribute__((ext_vector_type(8))) _Float16 f16x8;
typedef __attribute__((ext_vector_type(4))) float f32x4;

__device__ __forceinline__ void gll16(const void* g, void* l) {
  __builtin_amdgcn_global_load_lds((const __attribute__((address_space(1))) void*)g,
                                   (__attribute__((address_space(3))) void*)l, 16, 0, 0);
}

struct alignas(8) H4 { f16 a, b, c, d; };

// ---------------- GEMM (NT): C[M,N] = A[M,K] * W[N,K]^T
// 2-phase double-buffered (proven structure), 128x128 block, BK=32,
// 4 waves (2x2), wave tile 64x64, all staging via global_load_lds.
// MODE 0: split f16 (hi/lo planes, lo pre-scaled 2^12), f32 out
// MODE 1: plain f16, epilogue computes softmax inline from attn partials
//         (extra = attn_p) and scales; f16 out
// MODE 2: plain f16, epilogue adds bias (extra = bias), f32 out
template <int MODE>
__global__ __launch_bounds__(256, (MODE == 0) ? 2 : 4)
void gemm_nt(const f16* __restrict__ Ah, const f16* __restrict__ Al,
             const f16* __restrict__ Wh, const f16* __restrict__ Wl,
             void* __restrict__ Cp, const float* __restrict__ extra,
             int M, int K, int ldc, int ntiles) {
  constexpr int BUF = (MODE == 0) ? 32768 : 16384;   // bytes per buffer
  constexpr int BO  = (MODE == 0) ? 16384 : 8192;    // B region offset
  __shared__ alignas(16) char lds[2 * BUF];
  const int tid = threadIdx.x;
  const int w = tid >> 6;
  const int lane = tid & 63;

  // XCD-chunked bijective remap: consecutive wid share an A-panel
  const int nwg = gridDim.x;
  const int orig = blockIdx.x;
  const int qq = nwg >> 3, rr = nwg & 7;
  const int xcd = orig & 7;
  const int wid = (xcd < rr ? xcd * (qq + 1) : rr * (qq + 1) + (xcd - rr) * qq) + (orig >> 3);
  const int bm = (wid / ntiles) * 128;
  const int bn = (wid % ntiles) * 128;

  f32x4 accA[4][4] = {};
  f32x4 accB[4][4];
  if constexpr (MODE == 0) {
#pragma unroll
    for (int i = 0; i < 4; ++i)
#pragma unroll
      for (int j = 0; j < 4; ++j) accB[i][j] = f32x4{0.f, 0.f, 0.f, 0.f};
  }

  // staging: LDS linear dest, pre-swizzled global source slot
  const int srow = tid >> 2;                                   // 0..63
  const int gslot = (tid & 3) ^ ((srow & 3) ^ ((srow >> 2) & 3));
  int ar0 = bm + srow;      if (ar0 > M - 1) ar0 = M - 1;
  int ar1 = bm + 64 + srow; if (ar1 > M - 1) ar1 = M - 1;
  const f16* pAh0 = Ah + (size_t)ar0 * K + gslot * 8;
  const f16* pAh1 = Ah + (size_t)ar1 * K + gslot * 8;
  const f16* pBh0 = Wh + (size_t)(bn + srow) * K + gslot * 8;
  const f16* pBh1 = Wh + (size_t)(bn + 64 + srow) * K + gslot * 8;
  const f16* pAl0 = nullptr; const f16* pAl1 = nullptr;
  const f16* pBl0 = nullptr; const f16* pBl1 = nullptr;
  if constexpr (MODE == 0) {
    pAl0 = Al + (size_t)ar0 * K + gslot * 8;
    pAl1 = Al + (size_t)ar1 * K + gslot * 8;
    pBl0 = Wl + (size_t)(bn + srow) * K + gslot * 8;
    pBl1 = Wl + (size_t)(bn + 64 + srow) * K + gslot * 8;
  }
  const int wb = w << 10;

  // MFMA fragment read offsets (bytes, plane-local)
  const int fr = lane & 15;
  const int g = lane >> 4;
  const int wm = (w >> 1) * 64;
  const int wn = (w & 1) * 64;
  int aoff[4], boff[4];
#pragma unroll
  for (int i = 0; i < 4; ++i) {
    int row = wm + i * 16 + fr;
    aoff[i] = row * 64 + ((g ^ ((row & 3) ^ ((row >> 2) & 3))) * 16);
    int col = wn + i * 16 + fr;
    boff[i] = col * 64 + ((g ^ ((col & 3) ^ ((col >> 2) & 3))) * 16);
  }

  auto STAGE = [&](int bufo, int kt) {
    char* dst = lds + bufo;
    gll16(pAh0 + kt, dst + wb);
    gll16(pAh1 + kt, dst + 4096 + wb);
    gll16(pBh0 + kt, dst + BO + wb);
    gll16(pBh1 + kt, dst + BO + 4096 + wb);
    if constexpr (MODE == 0) {
      gll16(pAl0 + kt, dst + 8192 + wb);
      gll16(pAl1 + kt, dst + 12288 + wb);
      gll16(pBl0 + kt, dst + BO + 8192 + wb);
      gll16(pBl1 + kt, dst + BO + 12288 + wb);
    }
  };

  auto COMPUTE = [&](int bufo) {
    const char* base = lds + bufo;
    f16x8 ah[4], bh[4];
#pragma unroll
    for (int i = 0; i < 4; ++i) ah[i] = *(const f16x8*)(base + aoff[i]);
#pragma unroll
    for (int j = 0; j < 4; ++j) bh[j] = *(const f16x8*)(base + BO + boff[j]);
#pragma unroll
    for (int i = 0; i < 4; ++i)
#pragma unroll
      for (int j = 0; j < 4; ++j)
        accA[i][j] = __builtin_amdgcn_mfma_f32_16x16x32_f16(ah[i], bh[j], accA[i][j], 0, 0, 0);
    if constexpr (MODE == 0) {
      f16x8 bl[4];
#pragma unroll
      for (int j = 0; j < 4; ++j) bl[j] = *(const f16x8*)(base + BO + 8192 + boff[j]);
#pragma unroll
      for (int i = 0; i < 4; ++i)
#pragma unroll
        for (int j = 0; j < 4; ++j)
          accB[i][j] = __builtin_amdgcn_mfma_f32_16x16x32_f16(ah[i], bl[j], accB[i][j], 0, 0, 0);
      f16x8 al[4];
#pragma unroll
      for (int i = 0; i < 4; ++i) al[i] = *(const f16x8*)(base + 8192 + aoff[i]);
#pragma unroll
      for (int i = 0; i < 4; ++i)
#pragma unroll
        for (int j = 0; j < 4; ++j)
          accB[i][j] = __builtin_amdgcn_mfma_f32_16x16x32_f16(al[i], bh[j], accB[i][j], 0, 0, 0);
    }
  };

  STAGE(0, 0);
  __syncthreads();
  const int nk = K >> 5;
  for (int t = 0; t < nk; ++t) {
    const int cur = (t & 1) ? BUF : 0;
    if (t + 1 < nk) STAGE(cur ^ BUF, (t + 1) << 5);
    COMPUTE(cur);
    __syncthreads();    // drains vmcnt(0)+lgkmcnt(0): next buffer ready, this buffer free
  }

  // MODE 1: inline softmax — each wave computes weights for one (batch, head)
  const int b_first = bm / 197;
  if constexpr (MODE == 1) {
    float* law = (float*)lds;               // [4][200]: slot = bi*2 + hi
    const int bi = w >> 1, hi = w & 1;
    int bb = b_first + bi; if (bb > 63) bb = 63;
    const int hh = (bn >> 6) + hi;
    const float* ap = extra + (size_t)(bb * 12 + hh) * 197;
    float v4[4];
#pragma unroll
    for (int j = 0; j < 4; ++j) {
      int n = j * 64 + lane;
      float s = -1e30f;
      if (n < 197) {
        s = 0.f;
#pragma unroll
        for (int c = 0; c < 8; ++c) s += ap[(size_t)c * 151296 + n];
      }
      v4[j] = s;
    }
    float m = fmaxf(fmaxf(v4[0], v4[1]), fmaxf(v4[2], v4[3]));
#pragma unroll
    for (int o = 32; o; o >>= 1) m = fmaxf(m, __shfl_xor(m, o, 64));
    float e4[4];
    float sum = 0.f;
#pragma unroll
    for (int j = 0; j < 4; ++j) {
      int n = j * 64 + lane;
      e4[j] = (n < 197) ? expf(v4[j] - m) : 0.f;
      sum += e4[j];
    }
#pragma unroll
    for (int o = 32; o; o >>= 1) sum += __shfl_xor(sum, o, 64);
    float inv = 1.f / sum;
#pragma unroll
    for (int j = 0; j < 4; ++j) {
      int n = j * 64 + lane;
      if (n < 197) law[w * 200 + n] = e4[j] * inv;
    }
    __syncthreads();
  }

#pragma unroll
  for (int i = 0; i < 4; ++i) {
#pragma unroll
    for (int j = 0; j < 4; ++j) {
#pragma unroll
      for (int r = 0; r < 4; ++r) {
        int row = bm + wm + i * 16 + g * 4 + r;
        int col = bn + wn + j * 16 + fr;
        if (row < M) {
          float v = accA[i][j][r];
          if constexpr (MODE == 0) {
            v += accB[i][j][r] * (1.0f / 4096.0f);
            ((float*)Cp)[(size_t)row * ldc + col] = v;
          } else if constexpr (MODE == 1) {
            int b = row / 197;
            int n = row - b * 197;
            int bi2 = b - b_first;
            float aw = ((const float*)lds)[(bi2 * 2 + (w & 1)) * 200 + n];
            ((f16*)Cp)[(size_t)row * ldc + col] = (f16)(aw * v);
          } else {
            ((float*)Cp)[(size_t)row * ldc + col] = v + extra[col];
          }
        }
      }
    }
  }
}

// ---------------- merged prep (x split row-major, v/proj weight packs) + fold (wq/wk)
// fold blocks XCD-grouped: all 64 e-members of a (s,h) group share orig%8 -> one
// XCD L2 fetches each 196KB qkv_w panel once (was 8x).
__global__ __launch_bounds__(256) void prep_fold(const float* __restrict__ x,
                                                 const float* __restrict__ qkv_w,
                                                 const float* __restrict__ wq,
                                                 const float* __restrict__ wk,
                                                 const float* __restrict__ proj_w,
                                                 f16* __restrict__ Ah, f16* __restrict__ Al,
                                                 f16* __restrict__ Wh, f16* __restrict__ Wl,
                                                 f16* __restrict__ Pw) {
  __shared__ float wv[64];
  const int t = threadIdx.x;
  if (blockIdx.x < 1536) {
    // bijective remap on [0,1536): grp=(s,h) in [0,24), e=member
    const int orig = blockIdx.x;
    const int grp = (orig & 7) + 8 * ((orig >> 3) >> 6);   // (orig>>3)/64 in {0,1,2}
    const int e = (orig >> 3) & 63;
    const int s = grp / 12;
    const int h = grp - s * 12;
    if (t < 64) {
      const float* w = (s == 0) ? wq : wk;
      wv[t] = w[(size_t)(h * 64 + t) * 64 + e];
    }
    __syncthreads();
    const float* base = qkv_w + (size_t)(s * 768 + h * 64) * 768;
    float acc0 = 0.f, acc1 = 0.f, acc2 = 0.f;
#pragma unroll 8
    for (int d = 0; d < 64; ++d) {
      float w = wv[d];
      const float* rowp = base + (size_t)d * 768;
      acc0 += w * rowp[t];
      acc1 += w * rowp[t + 256];
      acc2 += w * rowp[t + 512];
    }
    size_t ro = (size_t)(s * 768 + h * 64 + e) * 768;
    f16 h0 = (f16)acc0, h1 = (f16)acc1, h2 = (f16)acc2;
    Wh[ro + t]       = h0; Wl[ro + t]       = (f16)((acc0 - (float)h0) * 4096.f);
    Wh[ro + t + 256] = h1; Wl[ro + t + 256] = (f16)((acc1 - (float)h1) * 4096.f);
    Wh[ro + t + 512] = h2; Wl[ro + t + 512] = (f16)((acc2 - (float)h2) * 4096.f);
    return;
  }
  const int X4 = 2420736;   // 12608*768/4
  const int V4 = 147456;    // 768*768/4
  int i = (blockIdx.x - 1536) * 256 + t;
  if (i < X4) {
    float4 v = ((const float4*)x)[i];
    H4 hi, lo;
    hi.a = (f16)v.x; hi.b = (f16)v.y; hi.c = (f16)v.z; hi.d = (f16)v.w;
    lo.a = (f16)((v.x - (float)hi.a) * 4096.f);
    lo.b = (f16)((v.y - (float)hi.b) * 4096.f);
    lo.c = (f16)((v.z - (float)hi.c) * 4096.f);
    lo.d = (f16)((v.w - (float)hi.d) * 4096.f);
    ((H4*)Ah)[i] = hi; ((H4*)Al)[i] = lo;
  } else if (i < X4 + V4) {
    int j = i - X4;
    float4 v = ((const float4*)(qkv_w + (size_t)1536 * 768))[j];
    H4 h; h.a = (f16)v.x; h.b = (f16)v.y; h.c = (f16)v.z; h.d = (f16)v.w;
    ((H4*)(Wh + (size_t)1536 * 768))[j] = h;
  } else if (i < X4 + 2 * V4) {
    int j = i - X4 - V4;
    float4 v = ((const float4*)proj_w)[j];
    H4 h; h.a = (f16)v.x; h.b = (f16)v.y; h.c = (f16)v.z; h.d = (f16)v.w;
    ((H4*)Pw)[j] = h;
  }
}

// ---------------- 2D DFT-14 logits, compile-time twiddles
__device__ constexpr float CS14[14] = {
  1.0f,  0.90096886790241915f,  0.62348980185873359f,  0.22252093395631440f,
 -0.22252093395631440f, -0.62348980185873359f, -0.90096886790241915f, -1.0f,
 -0.90096886790241915f, -0.62348980185873359f, -0.22252093395631440f,
  0.22252093395631440f,  0.62348980185873359f,  0.90096886790241915f };
__device__ constexpr float SN14[14] = {
  0.0f, -0.43388373911755823f, -0.78183148246802980f, -0.97492791218182362f,
 -0.97492791218182362f, -0.78183148246802980f, -0.43388373911755823f,  0.0f,
  0.43388373911755823f,  0.78183148246802980f,  0.97492791218182362f,
  0.97492791218182362f,  0.78183148246802980f,  0.43388373911755823f };
// W7^k = exp(-2*pi*i*k/7)
__device__ constexpr float CS7[7] = {
  1.0f,  0.62348980185873359f, -0.22252093395631440f, -0.90096886790241915f,
 -0.90096886790241915f, -0.22252093395631440f,  0.62348980185873359f };
__device__ constexpr float SN7[7] = {
  0.0f, -0.78183148246802980f, -0.97492791218182362f, -0.43388373911755823f,
  0.43388373911755823f,  0.97492791218182362f,  0.78183148246802980f };

// radix-2 column-DFT pair: computes L[f1=U] and L[f1=U+7] for one (f2,e) column.
template <int U>
__device__ __forceinline__ void colpair(const float (&qr)[14], const float (&qi)[14],
                                        const float (&kr)[14], const float (&ki)[14],
                                        float& Lu, float& Lu7) {
  float Eqr = 0.f, Eqi = 0.f, Oqr = 0.f, Oqi = 0.f;
  float Ekr = 0.f, Eki = 0.f, Okr = 0.f, Oki = 0.f;
#pragma unroll
  for (int m = 0; m < 7; ++m) {
    const float c = CS7[(m * U) % 7], s = SN7[(m * U) % 7];
    Eqr += qr[2 * m] * c - qi[2 * m] * s;
    Eqi += qr[2 * m] * s + qi[2 * m] * c;
    Oqr += qr[2 * m + 1] * c - qi[2 * m + 1] * s;
    Oqi += qr[2 * m + 1] * s + qi[2 * m + 1] * c;
    Ekr += kr[2 * m] * c - ki[2 * m] * s;
    Eki += kr[2 * m] * s + ki[2 * m] * c;
    Okr += kr[2 * m + 1] * c - ki[2 * m + 1] * s;
    Oki += kr[2 * m + 1] * s + ki[2 * m + 1] * c;
  }
  const float wc = CS14[U], ws = SN14[U];
  const float WOqr = Oqr * wc - Oqi * ws, WOqi = Oqr * ws + Oqi * wc;
  const float WOkr = Okr * wc - Oki * ws, WOki = Okr * ws + Oki * wc;
  Lu  = (Eqr + WOqr) * (Ekr + WOkr) + (Eqi + WOqi) * (Eki + WOki);
  Lu7 = (Eqr - WOqr) * (Ekr - WOkr) + (Eqi - WOqi) * (Eki - WOki);
}

// per-(b,h,e-chunk of 8): row DFT (f2 half-spectrum) -> fused radix-2 col DFT
// + product + e-reduce
__global__ __launch_bounds__(256, 5) void fourier_logits(const float* __restrict__ Cq,
                                                         float* __restrict__ attn_part) {
  const int bid = blockIdx.x;
  const int bh = bid % 768;
  const int chunk = bid / 768;
  const int b = bh / 12, h = bh - b * 12;
  const int t = threadIdx.x;

  __shared__ float qt_s[8][201], kt_s[8][201];
  __shared__ float QRr[8][8][15], QRi[8][8][15], KRr[8][8][15], KRi[8][8][15];

  const float* baseq = Cq + (size_t)(b * 197) * 1536 + h * 64 + chunk * 8;
  for (int i = t; i < 197 * 8; i += 256) {
    int e = i & 7, n = i >> 3;
    qt_s[e][n] = baseq[(size_t)n * 1536 + e];
    kt_s[e][n] = baseq[(size_t)n * 1536 + 768 + e];
  }
  __syncthreads();

  {
    const int qk = t >> 7, e = (t >> 4) & 7, r = t & 15;
    if (r < 14) {
      const float* src = (qk ? kt_s[e] : qt_s[e]) + 1 + r * 14;
      float x[14];
#pragma unroll
      for (int s = 0; s < 14; ++s) x[s] = src[s];
      float (*Rr)[15] = qk ? KRr[e] : QRr[e];
      float (*Ri)[15] = qk ? KRi[e] : QRi[e];
#pragma unroll
      for (int f2 = 0; f2 < 8; ++f2) {
        float re = 0.f, im = 0.f;
#pragma unroll
        for (int s = 0; s < 14; ++s) {
          re += x[s] * CS14[(s * f2) % 14];
          im += x[s] * SN14[(s * f2) % 14];
        }
        Rr[f2][r] = re;
        Ri[f2][r] = im;
      }
    }
  }
  __syncthreads();

  {
    const int f1g = t >> 6, f2 = (t >> 3) & 7, e = t & 7;
    float qr[14], qi[14], kr[14], ki[14];
#pragma unroll
    for (int r = 0; r < 14; ++r) {
      qr[r] = QRr[e][f2][r]; qi[r] = QRi[e][f2][r];
      kr[r] = KRr[e][f2][r]; ki[r] = KRi[e][f2][r];
    }
    float* out = attn_part + (size_t)chunk * 151296 + (size_t)bh * 197;
    auto emit = [&](int f1, float L) {
      L += __shfl_xor(L, 1, 64);
      L += __shfl_xor(L, 2, 64);
      L += __shfl_xor(L, 4, 64);
      if (e == 0) {
        out[1 + f1 * 14 + f2] = L;
        if (f2 >= 1 && f2 <= 6) out[1 + ((14 - f1) % 14) * 14 + (14 - f2)] = L;
      }
    };
    float a, c;
    if (f1g == 0) {
      colpair<0>(qr, qi, kr, ki, a, c); emit(0, a); emit(7, c);
      colpair<1>(qr, qi, kr, ki, a, c); emit(1, a); emit(8, c);
    } else if (f1g == 1) {
      colpair<2>(qr, qi, kr, ki, a, c); emit(2, a); emit(9, c);
      colpair<3>(qr, qi, kr, ki, a, c); emit(3, a); emit(10, c);
    } else if (f1g == 2) {
      colpair<4>(qr, qi, kr, ki, a, c); emit(4, a); emit(11, c);
      colpair<5>(qr, qi, kr, ki, a, c); emit(5, a); emit(12, c);
    } else {
      colpair<6>(qr, qi, kr, ki, a, c); emit(6, a); emit(13, c);
    }
    if (t < 8) {
      float cls = qt_s[t][0] * kt_s[t][0];
      cls += __shfl_xor(cls, 1, 64);
      cls += __shfl_xor(cls, 2, 64);
      cls += __shfl_xor(cls, 4, 64);
      if (t == 0) out[0] = cls;
    }
  }
}

extern "C" void kernel_launch(void* const* d_in, const int* in_sizes, int n_in,
                              void* d_out, int out_size, void* d_ws, size_t ws_size,
                              hipStream_t stream) {
  const float* x      = (const float*)d_in[0];
  const float* qkv_w  = (const float*)d_in[1];
  const float* wq     = (const float*)d_in[2];
  const float* wk     = (const float*)d_in[3];
  const float* proj_w = (const float*)d_in[4];
  const float* proj_b = (const float*)d_in[5];

  char* ws = (char*)d_ws;
  float* Cq     = (float*)ws;                      // 12608*1536*4 = 77,463,552
  f16*   Ah     = (f16*)(ws + 77463552);           // row-major, 19,365,888
  f16*   Al     = (f16*)(ws + 96829440);           // row-major, 19,365,888
  f16*   Wh     = (f16*)(ws + 116195328);          // 2304*768*2 = 3,538,944
  f16*   Wl     = (f16*)(ws + 119734272);          // 1536*768*2 = 2,359,296
  f16*   Pw     = (f16*)(ws + 122093568);          // 1,179,648
  float* attn_p = (float*)(ws + 123273216);        // 8*768*197*4 = 4,841,472
  f16*   out_pre= (f16*)(ws + 128719872);          // 19,365,888

  prep_fold<<<12144, 256, 0, stream>>>(x, qkv_w, wq, wk, proj_w, Ah, Al, Wh, Wl, Pw);
  gemm_nt<0><<<1188, 256, 0, stream>>>(Ah, Al, Wh, Wl, Cq, nullptr, 12608, 768, 1536, 12);
  fourier_logits<<<6144, 256, 0, stream>>>(Cq, attn_p);
  gemm_nt<1><<<594, 256, 0, stream>>>(Ah, nullptr, Wh + (size_t)1536 * 768, nullptr,
                                      out_pre, attn_p, 12608, 768, 768, 6);
  gemm_nt<2><<<594, 256, 0, stream>>>(out_pre, nullptr, Pw, nullptr,
                                      d_out, proj_b, 12608, 768, 768, 6);
}

// Round 16
// 231.411 us; speedup vs baseline: 1.0103x; 1.0103x over previous
//
#include <hip/hip_runtime.h>

typedef _Float16 f16;
typedef __attribute__((ext_vector_type(8))) _Float16 f16x8;
typedef __attribute__((ext_vector_type(4))) float f32x4;

__device__ __forceinline__ void gll16(const void* g, void* l) {
  __builtin_amdgcn_global_load_lds((const __attribute__((address_space(1))) void*)g,
                                   (__attribute__((address_space(3))) void*)l, 16, 0, 0);
}

struct alignas(8) H4 { f16 a, b, c, d; };

// ---------------- GEMM (NT): C[M,N] = A[M,K] * W[N,K]^T
// 2-phase double-buffered (proven structure), 128x128 block, BK=32,
// 4 waves (2x2), wave tile 64x64, all staging via global_load_lds.
// MODE 0: split f16 (hi/lo planes, lo pre-scaled 2^12), f32 out
// MODE 1: plain f16, epilogue computes softmax inline from attn partials
//         (extra = attn_p) and scales; f16 out
// MODE 2: plain f16, epilogue adds bias (extra = bias), f32 out
template <int MODE>
__global__ __launch_bounds__(256, (MODE == 0) ? 2 : 4)
void gemm_nt(const f16* __restrict__ Ah, const f16* __restrict__ Al,
             const f16* __restrict__ Wh, const f16* __restrict__ Wl,
             void* __restrict__ Cp, const float* __restrict__ extra,
             int M, int K, int ldc, int ntiles) {
  constexpr int BUF = (MODE == 0) ? 32768 : 16384;   // bytes per buffer
  constexpr int BO  = (MODE == 0) ? 16384 : 8192;    // B region offset
  __shared__ alignas(16) char lds[2 * BUF];
  const int tid = threadIdx.x;
  const int w = tid >> 6;
  const int lane = tid & 63;

  // XCD-chunked bijective remap: consecutive wid share an A-panel
  const int nwg = gridDim.x;
  const int orig = blockIdx.x;
  const int qq = nwg >> 3, rr = nwg & 7;
  const int xcd = orig & 7;
  const int wid = (xcd < rr ? xcd * (qq + 1) : rr * (qq + 1) + (xcd - rr) * qq) + (orig >> 3);
  const int bm = (wid / ntiles) * 128;
  const int bn = (wid % ntiles) * 128;

  f32x4 accA[4][4] = {};
  f32x4 accB[4][4];
  if constexpr (MODE == 0) {
#pragma unroll
    for (int i = 0; i < 4; ++i)
#pragma unroll
      for (int j = 0; j < 4; ++j) accB[i][j] = f32x4{0.f, 0.f, 0.f, 0.f};
  }

  // staging: LDS linear dest, pre-swizzled global source slot
  const int srow = tid >> 2;                                   // 0..63
  const int gslot = (tid & 3) ^ ((srow & 3) ^ ((srow >> 2) & 3));
  int ar0 = bm + srow;      if (ar0 > M - 1) ar0 = M - 1;
  int ar1 = bm + 64 + srow; if (ar1 > M - 1) ar1 = M - 1;
  const f16* pAh0 = Ah + (size_t)ar0 * K + gslot * 8;
  const f16* pAh1 = Ah + (size_t)ar1 * K + gslot * 8;
  const f16* pBh0 = Wh + (size_t)(bn + srow) * K + gslot * 8;
  const f16* pBh1 = Wh + (size_t)(bn + 64 + srow) * K + gslot * 8;
  const f16* pAl0 = nullptr; const f16* pAl1 = nullptr;
  const f16* pBl0 = nullptr; const f16* pBl1 = nullptr;
  if constexpr (MODE == 0) {
    pAl0 = Al + (size_t)ar0 * K + gslot * 8;
    pAl1 = Al + (size_t)ar1 * K + gslot * 8;
    pBl0 = Wl + (size_t)(bn + srow) * K + gslot * 8;
    pBl1 = Wl + (size_t)(bn + 64 + srow) * K + gslot * 8;
  }
  const int wb = w << 10;

  // MFMA fragment read offsets (bytes, plane-local)
  const int fr = lane & 15;
  const int g = lane >> 4;
  const int wm = (w >> 1) * 64;
  const int wn = (w & 1) * 64;
  int aoff[4], boff[4];
#pragma unroll
  for (int i = 0; i < 4; ++i) {
    int row = wm + i * 16 + fr;
    aoff[i] = row * 64 + ((g ^ ((row & 3) ^ ((row >> 2) & 3))) * 16);
    int col = wn + i * 16 + fr;
    boff[i] = col * 64 + ((g ^ ((col & 3) ^ ((col >> 2) & 3))) * 16);
  }

  auto STAGE = [&](int bufo, int kt) {
    char* dst = lds + bufo;
    gll16(pAh0 + kt, dst + wb);
    gll16(pAh1 + kt, dst + 4096 + wb);
    gll16(pBh0 + kt, dst + BO + wb);
    gll16(pBh1 + kt, dst + BO + 4096 + wb);
    if constexpr (MODE == 0) {
      gll16(pAl0 + kt, dst + 8192 + wb);
      gll16(pAl1 + kt, dst + 12288 + wb);
      gll16(pBl0 + kt, dst + BO + 8192 + wb);
      gll16(pBl1 + kt, dst + BO + 12288 + wb);
    }
  };

  auto COMPUTE = [&](int bufo) {
    const char* base = lds + bufo;
    f16x8 ah[4], bh[4];
#pragma unroll
    for (int i = 0; i < 4; ++i) ah[i] = *(const f16x8*)(base + aoff[i]);
#pragma unroll
    for (int j = 0; j < 4; ++j) bh[j] = *(const f16x8*)(base + BO + boff[j]);
#pragma unroll
    for (int i = 0; i < 4; ++i)
#pragma unroll
      for (int j = 0; j < 4; ++j)
        accA[i][j] = __builtin_amdgcn_mfma_f32_16x16x32_f16(ah[i], bh[j], accA[i][j], 0, 0, 0);
    if constexpr (MODE == 0) {
      f16x8 bl[4];
#pragma unroll
      for (int j = 0; j < 4; ++j) bl[j] = *(const f16x8*)(base + BO + 8192 + boff[j]);
#pragma unroll
      for (int i = 0; i < 4; ++i)
#pragma unroll
        for (int j = 0; j < 4; ++j)
          accB[i][j] = __builtin_amdgcn_mfma_f32_16x16x32_f16(ah[i], bl[j], accB[i][j], 0, 0, 0);
      f16x8 al[4];
#pragma unroll
      for (int i = 0; i < 4; ++i) al[i] = *(const f16x8*)(base + 8192 + aoff[i]);
#pragma unroll
      for (int i = 0; i < 4; ++i)
#pragma unroll
        for (int j = 0; j < 4; ++j)
          accB[i][j] = __builtin_amdgcn_mfma_f32_16x16x32_f16(al[i], bh[j], accB[i][j], 0, 0, 0);
    }
  };

  STAGE(0, 0);
  __syncthreads();
  const int nk = K >> 5;
  for (int t = 0; t < nk; ++t) {
    const int cur = (t & 1) ? BUF : 0;
    if (t + 1 < nk) STAGE(cur ^ BUF, (t + 1) << 5);
    COMPUTE(cur);
    __syncthreads();    // drains vmcnt(0)+lgkmcnt(0): next buffer ready, this buffer free
  }

  // MODE 1: inline softmax — each wave computes weights for one (batch, head)
  const int b_first = bm / 197;
  if constexpr (MODE == 1) {
    float* law = (float*)lds;               // [4][200]: slot = bi*2 + hi
    const int bi = w >> 1, hi = w & 1;
    int bb = b_first + bi; if (bb > 63) bb = 63;
    const int hh = (bn >> 6) + hi;
    const float* ap = extra + (size_t)(bb * 12 + hh) * 197;
    float v4[4];
#pragma unroll
    for (int j = 0; j < 4; ++j) {
      int n = j * 64 + lane;
      float s = -1e30f;
      if (n < 197) {
        s = 0.f;
#pragma unroll
        for (int c = 0; c < 8; ++c) s += ap[(size_t)c * 151296 + n];
      }
      v4[j] = s;
    }
    float m = fmaxf(fmaxf(v4[0], v4[1]), fmaxf(v4[2], v4[3]));
#pragma unroll
    for (int o = 32; o; o >>= 1) m = fmaxf(m, __shfl_xor(m, o, 64));
    float e4[4];
    float sum = 0.f;
#pragma unroll
    for (int j = 0; j < 4; ++j) {
      int n = j * 64 + lane;
      e4[j] = (n < 197) ? expf(v4[j] - m) : 0.f;
      sum += e4[j];
    }
#pragma unroll
    for (int o = 32; o; o >>= 1) sum += __shfl_xor(sum, o, 64);
    float inv = 1.f / sum;
#pragma unroll
    for (int j = 0; j < 4; ++j) {
      int n = j * 64 + lane;
      if (n < 197) law[w * 200 + n] = e4[j] * inv;
    }
    __syncthreads();
  }

#pragma unroll
  for (int i = 0; i < 4; ++i) {
#pragma unroll
    for (int j = 0; j < 4; ++j) {
#pragma unroll
      for (int r = 0; r < 4; ++r) {
        int row = bm + wm + i * 16 + g * 4 + r;
        int col = bn + wn + j * 16 + fr;
        if (row < M) {
          float v = accA[i][j][r];
          if constexpr (MODE == 0) {
            v += accB[i][j][r] * (1.0f / 4096.0f);
            ((float*)Cp)[(size_t)row * ldc + col] = v;
          } else if constexpr (MODE == 1) {
            int b = row / 197;
            int n = row - b * 197;
            int bi2 = b - b_first;
            float aw = ((const float*)lds)[(bi2 * 2 + (w & 1)) * 200 + n];
            ((f16*)Cp)[(size_t)row * ldc + col] = (f16)(aw * v);
          } else {
            ((float*)Cp)[(size_t)row * ldc + col] = v + extra[col];
          }
        }
      }
    }
  }
}

// ---------------- merged prep (x split row-major, v/proj weight packs) + fold (wq/wk)
__global__ __launch_bounds__(256) void prep_fold(const float* __restrict__ x,
                                                 const float* __restrict__ qkv_w,
                                                 const float* __restrict__ wq,
                                                 const float* __restrict__ wk,
                                                 const float* __restrict__ proj_w,
                                                 f16* __restrict__ Ah, f16* __restrict__ Al,
                                                 f16* __restrict__ Wh, f16* __restrict__ Wl,
                                                 f16* __restrict__ Pw) {
  __shared__ float wv[64];
  const int t = threadIdx.x;
  if (blockIdx.x < 1536) {
    // fold: output row blk = s*768 + h*64 + e
    const int blk = blockIdx.x;
    const int s = blk / 768;
    const int he = blk - s * 768;
    const int h = he >> 6, e = he & 63;
    if (t < 64) {
      const float* w = (s == 0) ? wq : wk;
      wv[t] = w[(size_t)(h * 64 + t) * 64 + e];
    }
    __syncthreads();
    const float* base = qkv_w + (size_t)(s * 768 + h * 64) * 768;
    float acc0 = 0.f, acc1 = 0.f, acc2 = 0.f;
#pragma unroll 8
    for (int d = 0; d < 64; ++d) {
      float w = wv[d];
      const float* rowp = base + (size_t)d * 768;
      acc0 += w * rowp[t];
      acc1 += w * rowp[t + 256];
      acc2 += w * rowp[t + 512];
    }
    size_t ro = (size_t)blk * 768;
    f16 h0 = (f16)acc0, h1 = (f16)acc1, h2 = (f16)acc2;
    Wh[ro + t]       = h0; Wl[ro + t]       = (f16)((acc0 - (float)h0) * 4096.f);
    Wh[ro + t + 256] = h1; Wl[ro + t + 256] = (f16)((acc1 - (float)h1) * 4096.f);
    Wh[ro + t + 512] = h2; Wl[ro + t + 512] = (f16)((acc2 - (float)h2) * 4096.f);
    return;
  }
  const int X4 = 2420736;   // 12608*768/4
  const int V4 = 147456;    // 768*768/4
  int i = (blockIdx.x - 1536) * 256 + t;
  if (i < X4) {
    float4 v = ((const float4*)x)[i];
    H4 hi, lo;
    hi.a = (f16)v.x; hi.b = (f16)v.y; hi.c = (f16)v.z; hi.d = (f16)v.w;
    lo.a = (f16)((v.x - (float)hi.a) * 4096.f);
    lo.b = (f16)((v.y - (float)hi.b) * 4096.f);
    lo.c = (f16)((v.z - (float)hi.c) * 4096.f);
    lo.d = (f16)((v.w - (float)hi.d) * 4096.f);
    ((H4*)Ah)[i] = hi; ((H4*)Al)[i] = lo;
  } else if (i < X4 + V4) {
    int j = i - X4;
    float4 v = ((const float4*)(qkv_w + (size_t)1536 * 768))[j];
    H4 h; h.a = (f16)v.x; h.b = (f16)v.y; h.c = (f16)v.z; h.d = (f16)v.w;
    ((H4*)(Wh + (size_t)1536 * 768))[j] = h;
  } else if (i < X4 + 2 * V4) {
    int j = i - X4 - V4;
    float4 v = ((const float4*)proj_w)[j];
    H4 h; h.a = (f16)v.x; h.b = (f16)v.y; h.c = (f16)v.z; h.d = (f16)v.w;
    ((H4*)Pw)[j] = h;
  }
}

// ---------------- 2D DFT-14 logits, compile-time twiddles
__device__ constexpr float CS14[14] = {
  1.0f,  0.90096886790241915f,  0.62348980185873359f,  0.22252093395631440f,
 -0.22252093395631440f, -0.62348980185873359f, -0.90096886790241915f, -1.0f,
 -0.90096886790241915f, -0.62348980185873359f, -0.22252093395631440f,
  0.22252093395631440f,  0.62348980185873359f,  0.90096886790241915f };
__device__ constexpr float SN14[14] = {
  0.0f, -0.43388373911755823f, -0.78183148246802980f, -0.97492791218182362f,
 -0.97492791218182362f, -0.78183148246802980f, -0.43388373911755823f,  0.0f,
  0.43388373911755823f,  0.78183148246802980f,  0.97492791218182362f,
  0.97492791218182362f,  0.78183148246802980f,  0.43388373911755823f };
// W7^k = exp(-2*pi*i*k/7)
__device__ constexpr float CS7[7] = {
  1.0f,  0.62348980185873359f, -0.22252093395631440f, -0.90096886790241915f,
 -0.90096886790241915f, -0.22252093395631440f,  0.62348980185873359f };
__device__ constexpr float SN7[7] = {
  0.0f, -0.78183148246802980f, -0.97492791218182362f, -0.43388373911755823f,
  0.43388373911755823f,  0.97492791218182362f,  0.78183148246802980f };

// radix-2 column-DFT pair: computes L[f1=U] and L[f1=U+7] for one (f2,e) column.
template <int U>
__device__ __forceinline__ void colpair(const float (&qr)[14], const float (&qi)[14],
                                        const float (&kr)[14], const float (&ki)[14],
                                        float& Lu, float& Lu7) {
  float Eqr = 0.f, Eqi = 0.f, Oqr = 0.f, Oqi = 0.f;
  float Ekr = 0.f, Eki = 0.f, Okr = 0.f, Oki = 0.f;
#pragma unroll
  for (int m = 0; m < 7; ++m) {
    const float c = CS7[(m * U) % 7], s = SN7[(m * U) % 7];
    Eqr += qr[2 * m] * c - qi[2 * m] * s;
    Eqi += qr[2 * m] * s + qi[2 * m] * c;
    Oqr += qr[2 * m + 1] * c - qi[2 * m + 1] * s;
    Oqi += qr[2 * m + 1] * s + qi[2 * m + 1] * c;
    Ekr += kr[2 * m] * c - ki[2 * m] * s;
    Eki += kr[2 * m] * s + ki[2 * m] * c;
    Okr += kr[2 * m + 1] * c - ki[2 * m + 1] * s;
    Oki += kr[2 * m + 1] * s + ki[2 * m + 1] * c;
  }
  const float wc = CS14[U], ws = SN14[U];
  const float WOqr = Oqr * wc - Oqi * ws, WOqi = Oqr * ws + Oqi * wc;
  const float WOkr = Okr * wc - Oki * ws, WOki = Okr * ws + Oki * wc;
  Lu  = (Eqr + WOqr) * (Ekr + WOkr) + (Eqi + WOqi) * (Eki + WOki);
  Lu7 = (Eqr - WOqr) * (Ekr - WOkr) + (Eqi - WOqi) * (Eki - WOki);
}

// per-(b,h,e-chunk of 8): row DFT (f2 half-spectrum) -> fused radix-2 col DFT
// + product + e-reduce
__global__ __launch_bounds__(256, 5) void fourier_logits(const float* __restrict__ Cq,
                                                         float* __restrict__ attn_part) {
  const int bid = blockIdx.x;
  const int bh = bid % 768;
  const int chunk = bid / 768;
  const int b = bh / 12, h = bh - b * 12;
  const int t = threadIdx.x;

  __shared__ float qt_s[8][201], kt_s[8][201];
  __shared__ float QRr[8][8][15], QRi[8][8][15], KRr[8][8][15], KRi[8][8][15];

  const float* baseq = Cq + (size_t)(b * 197) * 1536 + h * 64 + chunk * 8;
  for (int i = t; i < 197 * 8; i += 256) {
    int e = i & 7, n = i >> 3;
    qt_s[e][n] = baseq[(size_t)n * 1536 + e];
    kt_s[e][n] = baseq[(size_t)n * 1536 + 768 + e];
  }
  __syncthreads();

  {
    const int qk = t >> 7, e = (t >> 4) & 7, r = t & 15;
    if (r < 14) {
      const float* src = (qk ? kt_s[e] : qt_s[e]) + 1 + r * 14;
      float x[14];
#pragma unroll
      for (int s = 0; s < 14; ++s) x[s] = src[s];
      float (*Rr)[15] = qk ? KRr[e] : QRr[e];
      float (*Ri)[15] = qk ? KRi[e] : QRi[e];
#pragma unroll
      for (int f2 = 0; f2 < 8; ++f2) {
        float re = 0.f, im = 0.f;
#pragma unroll
        for (int s = 0; s < 14; ++s) {
          re += x[s] * CS14[(s * f2) % 14];
          im += x[s] * SN14[(s * f2) % 14];
        }
        Rr[f2][r] = re;
        Ri[f2][r] = im;
      }
    }
  }
  __syncthreads();

  {
    const int f1g = t >> 6, f2 = (t >> 3) & 7, e = t & 7;
    float qr[14], qi[14], kr[14], ki[14];
#pragma unroll
    for (int r = 0; r < 14; ++r) {
      qr[r] = QRr[e][f2][r]; qi[r] = QRi[e][f2][r];
      kr[r] = KRr[e][f2][r]; ki[r] = KRi[e][f2][r];
    }
    float* out = attn_part + (size_t)chunk * 151296 + (size_t)bh * 197;
    auto emit = [&](int f1, float L) {
      L += __shfl_xor(L, 1, 64);
      L += __shfl_xor(L, 2, 64);
      L += __shfl_xor(L, 4, 64);
      if (e == 0) {
        out[1 + f1 * 14 + f2] = L;
        if (f2 >= 1 && f2 <= 6) out[1 + ((14 - f1) % 14) * 14 + (14 - f2)] = L;
      }
    };
    float a, c;
    if (f1g == 0) {
      colpair<0>(qr, qi, kr, ki, a, c); emit(0, a); emit(7, c);
      colpair<1>(qr, qi, kr, ki, a, c); emit(1, a); emit(8, c);
    } else if (f1g == 1) {
      colpair<2>(qr, qi, kr, ki, a, c); emit(2, a); emit(9, c);
      colpair<3>(qr, qi, kr, ki, a, c); emit(3, a); emit(10, c);
    } else if (f1g == 2) {
      colpair<4>(qr, qi, kr, ki, a, c); emit(4, a); emit(11, c);
      colpair<5>(qr, qi, kr, ki, a, c); emit(5, a); emit(12, c);
    } else {
      colpair<6>(qr, qi, kr, ki, a, c); emit(6, a); emit(13, c);
    }
    if (t < 8) {
      float cls = qt_s[t][0] * kt_s[t][0];
      cls += __shfl_xor(cls, 1, 64);
      cls += __shfl_xor(cls, 2, 64);
      cls += __shfl_xor(cls, 4, 64);
      if (t == 0) out[0] = cls;
    }
  }
}

extern "C" void kernel_launch(void* const* d_in, const int* in_sizes, int n_in,
                              void* d_out, int out_size, void* d_ws, size_t ws_size,
                              hipStream_t stream) {
  const float* x      = (const float*)d_in[0];
  const float* qkv_w  = (const float*)d_in[1];
  const float* wq     = (const float*)d_in[2];
  const float* wk     = (const float*)d_in[3];
  const float* proj_w = (const float*)d_in[4];
  const float* proj_b = (const float*)d_in[5];

  char* ws = (char*)d_ws;
  float* Cq     = (float*)ws;                      // 12608*1536*4 = 77,463,552
  f16*   Ah     = (f16*)(ws + 77463552);           // row-major, 19,365,888
  f16*   Al     = (f16*)(ws + 96829440);           // row-major, 19,365,888
  f16*   Wh     = (f16*)(ws + 116195328);          // 2304*768*2 = 3,538,944
  f16*   Wl     = (f16*)(ws + 119734272);          // 1536*768*2 = 2,359,296
  f16*   Pw     = (f16*)(ws + 122093568);          // 1,179,648
  float* attn_p = (float*)(ws + 123273216);        // 8*768*197*4 = 4,841,472
  f16*   out_pre= (f16*)(ws + 128719872);          // 19,365,888

  prep_fold<<<12144, 256, 0, stream>>>(x, qkv_w, wq, wk, proj_w, Ah, Al, Wh, Wl, Pw);
  gemm_nt<0><<<1188, 256, 0, stream>>>(Ah, Al, Wh, Wl, Cq, nullptr, 12608, 768, 1536, 12);
  fourier_logits<<<6144, 256, 0, stream>>>(Cq, attn_p);
  gemm_nt<1><<<594, 256, 0, stream>>>(Ah, nullptr, Wh + (size_t)1536 * 768, nullptr,
                                      out_pre, attn_p, 12608, 768, 768, 6);
  gemm_nt<2><<<594, 256, 0, stream>>>(out_pre, nullptr, Pw, nullptr,
                                      d_out, proj_b, 12608, 768, 768, 6);
}